// Round 10
// baseline (597.242 us; speedup 1.0000x reference)
//
#include <hip/hip_runtime.h>

#define T_TOK 1024
#define HD    2048
#define NE    64
#define ID    768
#define TOPK  8

typedef __bf16 bf16x8 __attribute__((ext_vector_type(8)));
typedef float  f32x4  __attribute__((ext_vector_type(4)));

#define VMC(N) asm volatile("s_waitcnt vmcnt(" N ")" ::: "memory")
#define BAR()  __builtin_amdgcn_s_barrier()
#define SCHED0 __builtin_amdgcn_sched_barrier(0)
#define FENCE  asm volatile("" ::: "memory")

__device__ __forceinline__ void load_lds16(const void* src, void* lds) {
  __builtin_amdgcn_global_load_lds(
      (const __attribute__((address_space(1))) void*)src,
      (__attribute__((address_space(3))) void*)lds, 16, 0, 0);
}

__device__ __forceinline__ bf16x8 cvt8(f32x4 a, f32x4 b) {
  bf16x8 r;
  #pragma unroll
  for (int j = 0; j < 4; ++j) { r[j] = (__bf16)a[j]; r[j + 4] = (__bf16)b[j]; }
  return r;
}

// ---------------------------------------------------------------------------
// Router: fp64 logits -> top-8 -> renormalized weights; per-expert lists;
// x -> bf16.
// ---------------------------------------------------------------------------
__global__ __launch_bounds__(256) void router_kernel(
    const float* __restrict__ x, const float* __restrict__ rw,
    unsigned short* __restrict__ xb_u, float* __restrict__ tw,
    int* __restrict__ counts, int* __restrict__ lists)
{
  __shared__ float  sx[HD];
  __shared__ double slog[NE];
  const int t = blockIdx.x;
  const int tid = threadIdx.x;
  __bf16* xb = (__bf16*)xb_u;

  for (int i = tid; i < HD; i += 256) {
    float v = x[(size_t)t * HD + i];
    sx[i] = v;
    xb[(size_t)t * HD + i] = (__bf16)v;
  }
  __syncthreads();

  const int e = tid >> 2, p = tid & 3;
  const float* rwrow = rw + (size_t)e * HD;
  double acc = 0.0;
  for (int k = p; k < HD; k += 4)
    acc += (double)sx[k] * (double)rwrow[k];
  acc += __shfl_xor(acc, 1, 64);
  acc += __shfl_xor(acc, 2, 64);
  if (p == 0) slog[e] = acc;
  __syncthreads();

  if (tid < 64) {
    double v = slog[tid];
    double selv = -1e300; int seli = 0; double gmax = 0.0;
    #pragma unroll
    for (int k = 0; k < TOPK; ++k) {
      double bv = v; int bi = tid;
      #pragma unroll
      for (int off = 32; off >= 1; off >>= 1) {
        double ov = __shfl_xor(bv, off, 64);
        int    oi = __shfl_xor(bi, off, 64);
        if (ov > bv || (ov == bv && oi < bi)) { bv = ov; bi = oi; }
      }
      if (k == 0) gmax = bv;
      if (tid == k) { selv = bv; seli = bi; }
      if (tid == bi) v = -1e300;
    }
    double e_ = (tid < TOPK) ? exp(selv - gmax) : 0.0;
    double s = e_;
    #pragma unroll
    for (int off = 32; off >= 1; off >>= 1) s += __shfl_xor(s, off, 64);
    if (tid < TOPK) {
      int slot = t * TOPK + tid;
      tw[slot] = (float)(e_ / s);
      int pos = atomicAdd(&counts[seli], 1);
      lists[seli * T_TOK + pos] = slot;
    }
  }
}

// ---------------------------------------------------------------------------
// GEMM1: block = (expert, 64 i-cols). M=192 tokens, BK=64, 32 K-steps.
// A double-buffered in LDS (2 x 24 KB) via global_load_lds (pre-swizzled
// src). Waves 0-3 stream 16 gate rows each, 4-7 up rows, straight to MFMA
// B-frag registers (4 f32x4/step, 2-set rotation, never vmcnt-drained).
// Per step: issue A(t+1)+W(t+1) -> compute(t) -> vmcnt(4) [A only] -> BAR.
// LDS ~50 KB, launch_bounds(512,4) => 2 blocks/CU: independent blocks
// fill each other's barrier stalls.
// ---------------------------------------------------------------------------
__global__ __launch_bounds__(512, 4) void gemm1_kernel(
    const unsigned short* __restrict__ xb_u,
    const float* __restrict__ gw, const float* __restrict__ uw,
    const int* __restrict__ counts, const int* __restrict__ lists,
    unsigned short* __restrict__ hb_u)
{
  __shared__ __bf16 sA[2][12288];   // 2 x 192 x 64 bf16 = 2 x 24 KB
  __shared__ int    sSlot[192];

  const char* xbp = (const char*)xb_u;
  __bf16* hb = (__bf16*)hb_u;
  char* sAc = (char*)&sA[0][0];

  // 768 blocks = 8 XCD chunks of 96 (12 n-tiles x 8 experts)
  const int wg  = blockIdx.x;
  const int idx = wg >> 3;
  const int e   = (wg & 7) * 8 + idx / 12;
  const int n0  = (idx % 12) * 64;
  const int tid = threadIdx.x, wid = tid >> 6, lane = tid & 63;
  const int n_e = counts[e];
  const int isu = wid >> 2;

  // per-lane W address: row = n0 + (wid&3)*16 + (lane&15); quarter q=lane>>4
  const char* wlane = (const char*)(isu ? uw : gw)
      + ((size_t)e * ID + n0 + (wid & 3) * 16 + (lane & 15)) * (size_t)(HD * 4)
      + (size_t)(lane >> 4) * 32;

#define STEP1(BUFC, CUR, NXT, KN, DOI)                                          \
  {                                                                             \
    if (DOI) {                                                                  \
      char* d_ = sAc + (1 - (BUFC)) * 24576 + wid * 3072;                       \
      load_lds16(aA0 + (size_t)(KN) * 128, d_);                                 \
      load_lds16(aA1 + (size_t)(KN) * 128, d_ + 1024);                          \
      load_lds16(aA2 + (size_t)(KN) * 128, d_ + 2048);                          \
      NXT[0] = *(const f32x4*)(wlane + (size_t)(KN) * 256);                     \
      NXT[1] = *(const f32x4*)(wlane + (size_t)(KN) * 256 + 16);                \
      NXT[2] = *(const f32x4*)(wlane + (size_t)(KN) * 256 + 128);               \
      NXT[3] = *(const f32x4*)(wlane + (size_t)(KN) * 256 + 144);               \
    }                                                                           \
    FENCE;                                                                      \
    {                                                                           \
      const char* rb_ = sAc + (BUFC) * 24576;                                   \
      bf16x8 bw0_ = cvt8(CUR[0], CUR[1]);                                       \
      bf16x8 bw1_ = cvt8(CUR[2], CUR[3]);                                       \
      const int c0_ = (lane >> 4), c1_ = 4 + (lane >> 4);                       \
      _Pragma("unroll") for (int g = 0; g < 12; ++g) if (g * 16 < rem) {        \
        const int tok_ = g * 16 + (lane & 15);                                  \
        bf16x8 a0_ = *(const bf16x8*)(rb_ + tok_ * 128 + ((c0_ ^ (tok_ & 7)) << 4)); \
        acc[g] = __builtin_amdgcn_mfma_f32_16x16x32_bf16(a0_, bw0_, acc[g], 0, 0, 0); \
        bf16x8 a1_ = *(const bf16x8*)(rb_ + tok_ * 128 + ((c1_ ^ (tok_ & 7)) << 4)); \
        acc[g] = __builtin_amdgcn_mfma_f32_16x16x32_bf16(a1_, bw1_, acc[g], 0, 0, 0); \
      }                                                                         \
    }                                                                           \
    if (DOI) { VMC("4"); } else { VMC("0"); }                                   \
    BAR(); SCHED0;                                                              \
  }

  for (int m0 = 0; m0 < n_e; m0 += 192) {
    __syncthreads();
    if (tid < 192) sSlot[tid] = (m0 + tid < n_e) ? lists[e * T_TOK + m0 + tid] : 0;
    __syncthreads();
    const int rem = (n_e - m0 < 192) ? (n_e - m0) : 192;

    // per-lane A source bases (pre-swizzled chunk -> linear LDS dst)
    const int r0 = wid * 24 + (lane >> 3);
    const int r1 = r0 + 8, r2 = r0 + 16;
    const char* aA0 = xbp + (size_t)(sSlot[r0] >> 3) * 4096 + (((lane & 7) ^ (r0 & 7)) << 4);
    const char* aA1 = xbp + (size_t)(sSlot[r1] >> 3) * 4096 + (((lane & 7) ^ (r1 & 7)) << 4);
    const char* aA2 = xbp + (size_t)(sSlot[r2] >> 3) * 4096 + (((lane & 7) ^ (r2 & 7)) << 4);

    f32x4 acc[12];
    #pragma unroll
    for (int g = 0; g < 12; ++g) acc[g] = (f32x4){0.f, 0.f, 0.f, 0.f};
    f32x4 wA[4], wB[4];

    // prologue: issue kc=0 into buf0/wA; drain A only
    {
      char* d_ = sAc + wid * 3072;
      load_lds16(aA0, d_);
      load_lds16(aA1, d_ + 1024);
      load_lds16(aA2, d_ + 2048);
      wA[0] = *(const f32x4*)(wlane);
      wA[1] = *(const f32x4*)(wlane + 16);
      wA[2] = *(const f32x4*)(wlane + 128);
      wA[3] = *(const f32x4*)(wlane + 144);
    }
    FENCE;
    VMC("4"); BAR(); SCHED0;

    #pragma unroll 1
    for (int it = 0; it < 15; ++it) {       // steps 0..29
      STEP1(0, wA, wB, 2 * it + 1, 1)
      STEP1(1, wB, wA, 2 * it + 2, 1)
    }
    STEP1(0, wA, wB, 31, 1)                 // step 30
    STEP1(1, wB, wA, 0, 0)                  // step 31

    // epilogue: u-waves publish via LDS; g-waves combine silu(g)*u
    if (isu) {
      #pragma unroll
      for (int g = 0; g < 12; ++g) if (g * 16 < rem)
        #pragma unroll
        for (int j = 0; j < 4; ++j) {
          int tok = g * 16 + (lane >> 4) * 4 + j;
          int cl = (wid & 3) * 16 + (lane & 15);
          *(float*)(sAc + tok * 256 + ((cl ^ ((tok & 3) << 4)) << 2)) = acc[g][j];
        }
    }
    __syncthreads();
    if (!isu) {
      #pragma unroll
      for (int g = 0; g < 12; ++g) if (g * 16 < rem)
        #pragma unroll
        for (int j = 0; j < 4; ++j) {
          int tok = g * 16 + (lane >> 4) * 4 + j;
          if (tok < rem) {
            int cl = (wid & 3) * 16 + (lane & 15);
            float uv = *(const float*)(sAc + tok * 256 + ((cl ^ ((tok & 3) << 4)) << 2));
            float gv = acc[g][j];
            int s = sSlot[tok];
            float hv = (gv / (1.0f + expf(-gv))) * uv;
            hb[(size_t)s * ID + (size_t)(n0 + cl)] = (__bf16)hv;
          }
        }
    }
    __syncthreads();
  }
#undef STEP1
}

// ---------------------------------------------------------------------------
// GEMM2: block = (expert, 128 H-cols). M=192, K=768, BK=64 (12 steps).
// Same pipeline; weighted atomic scatter to out.
// ---------------------------------------------------------------------------
__global__ __launch_bounds__(512, 4) void gemm2_kernel(
    const unsigned short* __restrict__ hb_u,
    const float* __restrict__ dw,
    const int* __restrict__ counts, const int* __restrict__ lists,
    const float* __restrict__ tw,
    float* __restrict__ out)
{
  __shared__ __bf16 sA[2][12288];
  __shared__ int    sSlot[192];

  const char* hbp = (const char*)hb_u;
  char* sAc = (char*)&sA[0][0];

  // 1024 blocks = 8 XCD chunks of 128 (16 n-tiles x 8 experts)
  const int wg  = blockIdx.x;
  const int idx = wg >> 3;
  const int e   = (wg & 7) * 8 + idx / 16;
  const int n0  = (idx % 16) * 128;
  const int tid = threadIdx.x, wid = tid >> 6, lane = tid & 63;
  const int n_e = counts[e];

  const char* wlane = (const char*)dw
      + ((size_t)e * HD + n0 + wid * 16 + (lane & 15)) * (size_t)(ID * 4)
      + (size_t)(lane >> 4) * 32;

#define STEP2(BUFC, CUR, NXT, KN, DOI)                                          \
  {                                                                             \
    if (DOI) {                                                                  \
      char* d_ = sAc + (1 - (BUFC)) * 24576 + wid * 3072;                       \
      load_lds16(aA0 + (size_t)(KN) * 128, d_);                                 \
      load_lds16(aA1 + (size_t)(KN) * 128, d_ + 1024);                          \
      load_lds16(aA2 + (size_t)(KN) * 128, d_ + 2048);                          \
      NXT[0] = *(const f32x4*)(wlane + (size_t)(KN) * 256);                     \
      NXT[1] = *(const f32x4*)(wlane + (size_t)(KN) * 256 + 16);                \
      NXT[2] = *(const f32x4*)(wlane + (size_t)(KN) * 256 + 128);               \
      NXT[3] = *(const f32x4*)(wlane + (size_t)(KN) * 256 + 144);               \
    }                                                                           \
    FENCE;                                                                      \
    {                                                                           \
      const char* rb_ = sAc + (BUFC) * 24576;                                   \
      bf16x8 bw0_ = cvt8(CUR[0], CUR[1]);                                       \
      bf16x8 bw1_ = cvt8(CUR[2], CUR[3]);                                       \
      const int c0_ = (lane >> 4), c1_ = 4 + (lane >> 4);                       \
      _Pragma("unroll") for (int g = 0; g < 12; ++g) if (g * 16 < rem) {        \
        const int tok_ = g * 16 + (lane & 15);                                  \
        bf16x8 a0_ = *(const bf16x8*)(rb_ + tok_ * 128 + ((c0_ ^ (tok_ & 7)) << 4)); \
        acc[g] = __builtin_amdgcn_mfma_f32_16x16x32_bf16(a0_, bw0_, acc[g], 0, 0, 0); \
        bf16x8 a1_ = *(const bf16x8*)(rb_ + tok_ * 128 + ((c1_ ^ (tok_ & 7)) << 4)); \
        acc[g] = __builtin_amdgcn_mfma_f32_16x16x32_bf16(a1_, bw1_, acc[g], 0, 0, 0); \
      }                                                                         \
    }                                                                           \
    if (DOI) { VMC("4"); } else { VMC("0"); }                                   \
    BAR(); SCHED0;                                                              \
  }

  for (int m0 = 0; m0 < n_e; m0 += 192) {
    __syncthreads();
    if (tid < 192) sSlot[tid] = (m0 + tid < n_e) ? lists[e * T_TOK + m0 + tid] : 0;
    __syncthreads();
    const int rem = (n_e - m0 < 192) ? (n_e - m0) : 192;

    const int r0 = wid * 24 + (lane >> 3);
    const int r1 = r0 + 8, r2 = r0 + 16;
    const char* aA0 = hbp + (size_t)sSlot[r0] * 1536 + (((lane & 7) ^ (r0 & 7)) << 4);
    const char* aA1 = hbp + (size_t)sSlot[r1] * 1536 + (((lane & 7) ^ (r1 & 7)) << 4);
    const char* aA2 = hbp + (size_t)sSlot[r2] * 1536 + (((lane & 7) ^ (r2 & 7)) << 4);

    f32x4 acc[12];
    #pragma unroll
    for (int g = 0; g < 12; ++g) acc[g] = (f32x4){0.f, 0.f, 0.f, 0.f};
    f32x4 wA[4], wB[4];

    {
      char* d_ = sAc + wid * 3072;
      load_lds16(aA0, d_);
      load_lds16(aA1, d_ + 1024);
      load_lds16(aA2, d_ + 2048);
      wA[0] = *(const f32x4*)(wlane);
      wA[1] = *(const f32x4*)(wlane + 16);
      wA[2] = *(const f32x4*)(wlane + 128);
      wA[3] = *(const f32x4*)(wlane + 144);
    }
    FENCE;
    VMC("4"); BAR(); SCHED0;

    #pragma unroll 1
    for (int it = 0; it < 5; ++it) {        // steps 0..9
      STEP2(0, wA, wB, 2 * it + 1, 1)
      STEP2(1, wB, wA, 2 * it + 2, 1)
    }
    STEP2(0, wA, wB, 11, 1)                 // step 10
    STEP2(1, wB, wA, 0, 0)                  // step 11

    // epilogue: weighted atomic scatter
    #pragma unroll
    for (int g = 0; g < 12; ++g) if (g * 16 < rem)
      #pragma unroll
      for (int j = 0; j < 4; ++j) {
        int tok = g * 16 + (lane >> 4) * 4 + j;
        if (tok < rem) {
          int s = sSlot[tok];
          float w = tw[s];
          atomicAdd(out + (size_t)(s >> 3) * HD + (size_t)(n0 + wid * 16 + (lane & 15)),
                    w * acc[g][j]);
        }
      }
  }
#undef STEP2
}

// ---------------------------------------------------------------------------
// Launcher. ws: xb bf16 | tw | counts | lists | hidden_buf bf16 (~17 MB).
// ---------------------------------------------------------------------------
extern "C" void kernel_launch(void* const* d_in, const int* in_sizes, int n_in,
                              void* d_out, int out_size, void* d_ws, size_t ws_size,
                              hipStream_t stream) {
  const float* x  = (const float*)d_in[0];
  const float* rw = (const float*)d_in[1];
  const float* gw = (const float*)d_in[2];
  const float* uw = (const float*)d_in[3];
  const float* dw = (const float*)d_in[4];
  float* out = (float*)d_out;

  char* ws = (char*)d_ws;
  const size_t XB_OFF  = 0;
  const size_t TW_OFF  = XB_OFF + (size_t)T_TOK * HD * 2;
  const size_t CNT_OFF = TW_OFF + (size_t)T_TOK * TOPK * 4;
  const size_t LST_OFF = CNT_OFF + 256;
  const size_t HB_OFF  = LST_OFF + (size_t)NE * T_TOK * 4;

  unsigned short* xb  = (unsigned short*)(ws + XB_OFF);
  float*          tw  = (float*)(ws + TW_OFF);
  int*            cnt = (int*)(ws + CNT_OFF);
  int*            lst = (int*)(ws + LST_OFF);
  unsigned short* hb  = (unsigned short*)(ws + HB_OFF);

  hipMemsetAsync(cnt, 0, 256, stream);
  hipMemsetAsync(d_out, 0, (size_t)T_TOK * HD * sizeof(float), stream);

  router_kernel<<<T_TOK, 256, 0, stream>>>(x, rw, xb, tw, cnt, lst);
  gemm1_kernel<<<768, 512, 0, stream>>>(xb, gw, uw, cnt, lst, hb);
  gemm2_kernel<<<1024, 512, 0, stream>>>(hb, dw, cnt, lst, tw, out);
}